// Round 6
// baseline (284.607 us; speedup 1.0000x reference)
//
#include <hip/hip_runtime.h>
#include <hip/hip_bf16.h>

#define B_    4
#define C_    256
#define HW    4096
#define N_    2048   // seq len after the (b,256,2048) reinterpretation
#define BSTR  524288 // 256*2048 elements per batch for phit/thetat/g/Yt

typedef unsigned short u16;
using f32x4 = __attribute__((ext_vector_type(4))) float;
using u32x4 = __attribute__((ext_vector_type(4))) unsigned int;

__device__ __forceinline__ float bf2f(u16 u) {
    return __uint_as_float(((unsigned)u) << 16);
}
__device__ __forceinline__ u16 f2bf(float f) {
    unsigned x = __float_as_uint(f);
    x += 0x7fff + ((x >> 16) & 1);   // RNE
    return (u16)(x >> 16);
}

// MFMA via inline asm. Hazards handled manually: chained same-acc MFMAs need
// no waits; VALU reads of acc go through mfma_fence; VALU-written operands
// get an s_nop-prefixed variant.
__device__ __forceinline__ void mfma_bf16(f32x4& acc, u32x4 a, u32x4 b) {
    asm volatile("v_mfma_f32_16x16x32_bf16 %0, %1, %2, %0"
                 : "+v"(acc) : "v"(a), "v"(b));
}
__device__ __forceinline__ void mfma_bf16_vsrc(f32x4& acc, u32x4 a, u32x4 b) {
    asm volatile("s_nop 1\n\tv_mfma_f32_16x16x32_bf16 %0, %1, %2, %0"
                 : "+v"(acc) : "v"(a), "v"(b));
}
__device__ __forceinline__ void mfma_fence(f32x4& x) {
    asm volatile("s_nop 7\n\ts_nop 7" : "+v"(x));
}

// ---------------------------------------------------------------------------
// prep_w: pack weights into Wt [640][512] bf16, k-fastest.
// ---------------------------------------------------------------------------
__global__ __launch_bounds__(256) void prep_w(
    const float* __restrict__ Wphi, const float* __restrict__ Wtheta,
    const float* __restrict__ Wg, const float* __restrict__ Wab,
    u16* __restrict__ Wt)
{
    const int row = blockIdx.x;          // 0..639
    const int t   = threadIdx.x;
    #pragma unroll
    for (int i = 0; i < 2; ++i) {
        const int col = i * 256 + t;
        float v;
        if (row < 128)      v = (col < 256)  ? Wphi[row * 256 + col] : 0.f;
        else if (row < 256) v = (col >= 256) ? Wtheta[(row - 128) * 256 + (col - 256)] : 0.f;
        else if (row < 384) v = Wg[(row - 256) * 512 + col];
        else                v = Wab[(row - 384) * 512 + col];
        Wt[row * 512 + col] = f2bf(v);
    }
}

// ---------------------------------------------------------------------------
// prep_abt: cast+transpose A,B (f32 [b][256][4096]) -> ABt bf16 [b][4096][512]
// ---------------------------------------------------------------------------
__global__ __launch_bounds__(256) void prep_abt(
    const float* __restrict__ A, const float* __restrict__ Bx,
    u16* __restrict__ ABt)
{
    __shared__ u16 L[64][528];
    const int t = threadIdx.x, pb = blockIdx.x, b = blockIdx.y;
    const int p0 = pb * 64;
    const int pl = t & 63, cg = t >> 6;
    const float* Ab = A  + (size_t)b * C_ * HW;
    const float* Bb = Bx + (size_t)b * C_ * HW;

    for (int i = 0; i < 64; ++i) {
        const int c = cg + i * 4;
        L[pl][c]       = f2bf(Ab[c * HW + p0 + pl]);
        L[pl][256 + c] = f2bf(Bb[c * HW + p0 + pl]);
    }
    __syncthreads();
    u16* dst = ABt + ((size_t)b * 4096 + p0) * 512;
    #pragma unroll
    for (int i = 0; i < 16; ++i) {
        const int idx = i * 256 + t;
        const int row = idx >> 6, ch = idx & 63;
        *(uint4*)&dst[row * 512 + ch * 8] = *(const uint4*)&L[row][ch * 8];
    }
}

// ---------------------------------------------------------------------------
// conv_gemm: C[o][p] = sum_k Wt[o][k] * ABt[p][k]  (per batch), o in [0,640).
// ---------------------------------------------------------------------------
__global__ __launch_bounds__(256) void conv_gemm(
    const u16* __restrict__ Wt, const u16* __restrict__ ABt,
    u16* __restrict__ phit, u16* __restrict__ thetat,
    u16* __restrict__ g, float* __restrict__ out)
{
    __shared__ __align__(16) u16 shW[64 * 128];
    __shared__ __align__(16) u16 shAB[64 * 128];
    const int t = threadIdx.x, pb = blockIdx.x, nb = blockIdx.y, b = blockIdx.z;
    const int lane = t & 63, w = t >> 6, lo = lane & 15, hi = lane >> 4;
    const u16* Wb = Wt + nb * 64 * 512;
    const u16* Ab = ABt + ((size_t)b * 4096 + pb * 64) * 512;

    f32x4 acc[4];
    #pragma unroll
    for (int ot = 0; ot < 4; ++ot) acc[ot] = (f32x4){0.f, 0.f, 0.f, 0.f};

    for (int ks = 0; ks < 4; ++ks) {
        __syncthreads();
        #pragma unroll
        for (int i = 0; i < 4; ++i) {
            const int q = i * 256 + t;
            const int row = q >> 4, c16 = (q & 15) * 8;
            const int sw = (row & 7) << 3;
            *(uint4*)&shW[row * 128 + (c16 ^ sw)]  = *(const uint4*)&Wb[row * 512 + ks * 128 + c16];
            *(uint4*)&shAB[row * 128 + (c16 ^ sw)] = *(const uint4*)&Ab[row * 512 + ks * 128 + c16];
        }
        __syncthreads();
        u32x4 bfr[4];
        {
            const int row = w * 16 + lo, sw = (row & 7) << 3;
            #pragma unroll
            for (int kf = 0; kf < 4; ++kf)
                bfr[kf] = *(const u32x4*)&shAB[row * 128 + ((kf * 32 + hi * 8) ^ sw)];
        }
        #pragma unroll
        for (int ot = 0; ot < 4; ++ot) {
            const int row = ot * 16 + lo, sw = (row & 7) << 3;
            #pragma unroll
            for (int kf = 0; kf < 4; ++kf) {
                const u32x4 a = *(const u32x4*)&shW[row * 128 + ((kf * 32 + hi * 8) ^ sw)];
                mfma_bf16(acc[ot], a, bfr[kf]);
            }
        }
    }

    const int p_global = pb * 64 + w * 16 + lo;
    const int m = p_global & 2047, h = p_global >> 11;
    #pragma unroll
    for (int ot = 0; ot < 4; ++ot) {
        mfma_fence(acc[ot]);
        const int ob = nb * 64 + ot * 16 + hi * 4;
        if (nb < 2) {
            ushort4 v;
            v.x = f2bf(acc[ot][0]); v.y = f2bf(acc[ot][1]);
            v.z = f2bf(acc[ot][2]); v.w = f2bf(acc[ot][3]);
            *(ushort4*)&phit[(size_t)b * BSTR + m * 256 + h * 128 + ob] = v;
        } else if (nb < 4) {
            ushort4 v;
            v.x = f2bf(acc[ot][0]); v.y = f2bf(acc[ot][1]);
            v.z = f2bf(acc[ot][2]); v.w = f2bf(acc[ot][3]);
            *(ushort4*)&thetat[(size_t)b * BSTR + m * 256 + h * 128 + (ob - 128)] = v;
        } else if (nb < 6) {
            #pragma unroll
            for (int q = 0; q < 4; ++q)
                g[(size_t)b * BSTR + (ob - 256 + q) * HW + p_global] = f2bf(acc[ot][q]);
        } else {
            #pragma unroll
            for (int q = 0; q < 4; ++q)
                out[(size_t)b * C_ * HW + (size_t)(ob - 384 + q) * HW + p_global] = acc[ot][q];
        }
    }
}

// ---------------------------------------------------------------------------
// Pass A (MFMA): partial row-sums of exp(S), S[m][n] = sum_c phit[m][c]*thetat[n][c].
// ---------------------------------------------------------------------------
__global__ __launch_bounds__(256) void passA_mfma(
    const u16* __restrict__ phit, const u16* __restrict__ thetat,
    float* __restrict__ rs)
{
    __shared__ __align__(16) u16 shP[64 * 256];
    __shared__ __align__(16) u16 shT[64 * 256];
    const int t = threadIdx.x, b = blockIdx.z, nq = blockIdx.y, mb = blockIdx.x;
    const u16* Pb = phit   + b * BSTR + mb * 64 * 256;
    const u16* Tb = thetat + b * BSTR + nq * 512 * 256;

    #pragma unroll
    for (int i = 0; i < 8; ++i) {
        const int q = i * 256 + t;
        const int row = q >> 5, c16 = (q & 31) * 8;
        const uint4 v = *(const uint4*)&Pb[row * 256 + c16];
        *(uint4*)&shP[row * 256 + (c16 ^ ((row & 7) << 3))] = v;
    }
    __syncthreads();

    const int lane = t & 63, w = t >> 6, lo = lane & 15, hi = lane >> 4;
    u32x4 afr[8];
    {
        const int row = w * 16 + lo;
        #pragma unroll
        for (int kb = 0; kb < 8; ++kb)
            afr[kb] = *(const u32x4*)&shP[row * 256 + ((kb * 32 + hi * 8) ^ ((row & 7) << 3))];
    }

    float rsacc[4] = {0.f, 0.f, 0.f, 0.f};
    for (int nt = 0; nt < 8; ++nt) {
        __syncthreads();
        #pragma unroll
        for (int i = 0; i < 8; ++i) {
            const int q = i * 256 + t;
            const int row = q >> 5, c16 = (q & 31) * 8;
            const uint4 v = *(const uint4*)&Tb[(nt * 64 + row) * 256 + c16];
            *(uint4*)&shT[row * 256 + (c16 ^ ((row & 7) << 3))] = v;
        }
        __syncthreads();
        #pragma unroll
        for (int ns = 0; ns < 4; ++ns) {
            f32x4 acc = {0.f, 0.f, 0.f, 0.f};
            const int row = ns * 16 + lo;
            #pragma unroll
            for (int kb = 0; kb < 8; ++kb) {
                const u32x4 bfr = *(const u32x4*)&shT[row * 256 + ((kb * 32 + hi * 8) ^ ((row & 7) << 3))];
                mfma_bf16(acc, afr[kb], bfr);
            }
            mfma_fence(acc);
            rsacc[0] += __expf(acc.x); rsacc[1] += __expf(acc.y);
            rsacc[2] += __expf(acc.z); rsacc[3] += __expf(acc.w);
        }
    }
    #pragma unroll
    for (int q = 0; q < 4; ++q) {
        float v = rsacc[q];
        v += __shfl_xor(v, 1); v += __shfl_xor(v, 2);
        v += __shfl_xor(v, 4); v += __shfl_xor(v, 8);
        rsacc[q] = v;
    }
    if (lo == 0) {
        const int m = mb * 64 + w * 16 + hi * 4;
        float* dst = rs + (nq * 4 + b) * N_ + m;
        dst[0] = rsacc[0]; dst[1] = rsacc[1]; dst[2] = rsacc[2]; dst[3] = rsacc[3];
    }
}

// ---------------------------------------------------------------------------
// g_scale: g[c][m] *= inv[m]  (fold softmax denominator into the PV A-operand)
// ---------------------------------------------------------------------------
__global__ __launch_bounds__(256) void g_scale(
    const float* __restrict__ rs, u16* __restrict__ g)
{
    const int t  = threadIdx.x;
    const int mt = blockIdx.x;       // 8 m-tiles of 256
    const int cg = blockIdx.y;       // 32 groups of 8 c''-rows
    const int b  = blockIdx.z;
    const int m  = mt * 256 + t;
    const float* rp = rs + b * N_ + m;
    const float inv = 1.0f / (rp[0] + rp[8192] + rp[16384] + rp[24576]);
    u16* gb = g + (size_t)b * BSTR + cg * 8 * N_ + m;
    #pragma unroll
    for (int j = 0; j < 8; ++j)
        gb[j * N_] = f2bf(bf2f(gb[j * N_]) * inv);
}

// ---------------------------------------------------------------------------
// Pass B (MFMA, flash-style): S computed ONCE per (n-tile, m-half); P=exp(S)
// in registers; PV over ALL 256 c'' rows. Yt partials per m-half.
//   grid (32 nb, 2 mh, 4 b). LDS: shT 32KB reused as shPm(16K)+shG(16K).
// ---------------------------------------------------------------------------
__global__ __launch_bounds__(256) void passB_mfma(
    const u16* __restrict__ phit, const u16* __restrict__ thetat,
    const u16* __restrict__ g, u16* __restrict__ ytp)
{
    __shared__ __align__(16) u16 shBuf[64 * 256];   // 32 KB
    u16* shT  = shBuf;            // [64][256] theta tile (prologue only)
    u16* shPm = shBuf;            // [32][256] phit m-step tile
    u16* shG  = shBuf + 32 * 256; // [256][32] g tile

    const int t = threadIdx.x, b = blockIdx.z, mh = blockIdx.y, nb = blockIdx.x;
    const u16* Tb = thetat + b * BSTR + nb * 64 * 256;
    const u16* Pb = phit   + b * BSTR + mh * 1024 * 256;
    const u16* Gb = g      + b * BSTR;
    const int lane = t & 63, w = t >> 6, lo = lane & 15, hi = lane >> 4;

    // prologue: stage theta, extract this wave's 8 B-frags, then free shT
    #pragma unroll
    for (int i = 0; i < 8; ++i) {
        const int q = i * 256 + t;
        const int row = q >> 5, c16 = (q & 31) * 8;
        const uint4 v = *(const uint4*)&Tb[row * 256 + c16];
        *(uint4*)&shT[row * 256 + (c16 ^ ((row & 7) << 3))] = v;
    }
    __syncthreads();
    u32x4 bfr[8];
    {
        const int row = w * 16 + lo;
        #pragma unroll
        for (int kb = 0; kb < 8; ++kb)
            bfr[kb] = *(const u32x4*)&shT[row * 256 + ((kb * 32 + hi * 8) ^ ((row & 7) << 3))];
    }
    __syncthreads();   // all frags extracted -> shBuf reusable

    f32x4 accY[16];
    #pragma unroll
    for (int ct = 0; ct < 16; ++ct) accY[ct] = (f32x4){0.f, 0.f, 0.f, 0.f};

    // prefetch m-step 0
    uint4 vp[4], vg[4];
    #pragma unroll
    for (int i = 0; i < 4; ++i) {
        const int q = i * 256 + t;
        vp[i] = *(const uint4*)&Pb[(q >> 5) * 256 + (q & 31) * 8];
    }
    #pragma unroll
    for (int qd = 0; qd < 4; ++qd)
        vg[qd] = *(const uint4*)&Gb[(size_t)t * N_ + mh * 1024 + qd * 8];

    for (int mt = 0; mt < 32; ++mt) {
        __syncthreads();   // previous compute done -> LDS writable
        #pragma unroll
        for (int i = 0; i < 4; ++i) {
            const int q = i * 256 + t;
            const int row = q >> 5, c16 = (q & 31) * 8;
            *(uint4*)&shPm[row * 256 + (c16 ^ ((row & 7) << 3))] = vp[i];
        }
        {
            const int sw = (t & 7) << 2, base = t * 32;
            #pragma unroll
            for (int qd = 0; qd < 4; ++qd) {
                const int m0 = qd * 8;
                *(uint2*)&shG[base + ((m0    ) ^ sw)] = make_uint2(vg[qd].x, vg[qd].y);
                *(uint2*)&shG[base + ((m0 + 4) ^ sw)] = make_uint2(vg[qd].z, vg[qd].w);
            }
        }
        // prefetch next m-step during compute
        const int mtn = (mt < 31) ? mt + 1 : 31;
        uint4 vp2[4], vg2[4];
        #pragma unroll
        for (int i = 0; i < 4; ++i) {
            const int q = i * 256 + t;
            vp2[i] = *(const uint4*)&Pb[(mtn * 32 + (q >> 5)) * 256 + (q & 31) * 8];
        }
        #pragma unroll
        for (int qd = 0; qd < 4; ++qd)
            vg2[qd] = *(const uint4*)&Gb[(size_t)t * N_ + mh * 1024 + mtn * 32 + qd * 8];
        __syncthreads();

        // S: this wave's 16 n-cols vs 32 m-rows
        f32x4 s0 = {0.f, 0.f, 0.f, 0.f}, s1 = {0.f, 0.f, 0.f, 0.f};
        {
            const int row = lo;
            #pragma unroll
            for (int kb = 0; kb < 8; ++kb) {
                const u32x4 a = *(const u32x4*)&shPm[row * 256 + ((kb * 32 + hi * 8) ^ ((row & 7) << 3))];
                mfma_bf16(s0, a, bfr[kb]);
            }
        }
        {
            const int row = 16 + lo;
            #pragma unroll
            for (int kb = 0; kb < 8; ++kb) {
                const u32x4 a = *(const u32x4*)&shPm[row * 256 + ((kb * 32 + hi * 8) ^ ((row & 7) << 3))];
                mfma_bf16(s1, a, bfr[kb]);
            }
        }
        mfma_fence(s0); mfma_fence(s1);

        // P = exp(S) (denominator pre-folded into g); pack bf16
        float p0[4], p1[4];
        #pragma unroll
        for (int q = 0; q < 4; ++q) {
            p0[q] = __expf(s0[q]);
            p1[q] = __expf(s1[q]);
        }
        u32x4 pf;
        pf[0] = (unsigned)f2bf(p0[0]) | ((unsigned)f2bf(p0[1]) << 16);
        pf[1] = (unsigned)f2bf(p0[2]) | ((unsigned)f2bf(p0[3]) << 16);
        pf[2] = (unsigned)f2bf(p1[0]) | ((unsigned)f2bf(p1[1]) << 16);
        pf[3] = (unsigned)f2bf(p1[2]) | ((unsigned)f2bf(p1[3]) << 16);

        // PV over all 16 c''-tiles
        #pragma unroll
        for (int ct = 0; ct < 16; ++ct) {
            const int row = ct * 16 + lo;
            const int sw = (row & 7) << 2, m4 = hi * 4;
            const uint2 a0 = *(const uint2*)&shG[row * 32 + ((m4     ) ^ sw)];
            const uint2 a1 = *(const uint2*)&shG[row * 32 + ((16 + m4) ^ sw)];
            u32x4 gf; gf[0] = a0.x; gf[1] = a0.y; gf[2] = a1.x; gf[3] = a1.y;
            mfma_bf16_vsrc(accY[ct], gf, pf);
        }

        #pragma unroll
        for (int i = 0; i < 4; ++i) vp[i] = vp2[i];
        #pragma unroll
        for (int qd = 0; qd < 4; ++qd) vg[qd] = vg2[qd];
    }

    // epilogue: Yt partial [mh][b][c''][n]
    u16* Yb = ytp + ((size_t)mh * B_ + b) * BSTR;
    const int col = nb * 64 + w * 16 + lo;
    #pragma unroll
    for (int ct = 0; ct < 16; ++ct) {
        mfma_fence(accY[ct]);
        const int crow = ct * 16 + hi * 4;
        #pragma unroll
        for (int q = 0; q < 4; ++q)
            Yb[(crow + q) * N_ + col] = f2bf(accY[ct][q]);
    }
}

// ---------------------------------------------------------------------------
// mask_add: out[o][p] += sum_k W_mask[o][k] * (Y0 + Y1)(128x4096)[k][p]
// ---------------------------------------------------------------------------
__global__ __launch_bounds__(256) void mask_add_kernel(
    const u16* __restrict__ ytp, const float* __restrict__ Wm,
    float* __restrict__ out)
{
    const int p  = blockIdx.x * 256 + threadIdx.x;
    const int og = blockIdx.y;
    const int b  = blockIdx.z;
    const u16* Y0 = ytp + (size_t)b * BSTR;
    const u16* Y1 = ytp + ((size_t)B_ + b) * BSTR;

    float acc[8] = {};
    for (int k = 0; k < 128; ++k) {
        const float y = bf2f(Y0[k * HW + p]) + bf2f(Y1[k * HW + p]);
        #pragma unroll
        for (int j = 0; j < 8; ++j)
            acc[j] = fmaf(Wm[(og * 8 + j) * 128 + k], y, acc[j]);
    }
    float* ob = out + (size_t)b * C_ * HW;
    #pragma unroll
    for (int j = 0; j < 8; ++j)
        ob[(og * 8 + j) * HW + p] += acc[j];
}

// ---------------------------------------------------------------------------
extern "C" void kernel_launch(void* const* d_in, const int* in_sizes, int n_in,
                              void* d_out, int out_size, void* d_ws, size_t ws_size,
                              hipStream_t stream)
{
    const float* A      = (const float*)d_in[0];
    const float* Bx     = (const float*)d_in[1];
    const float* Wphi   = (const float*)d_in[2];
    const float* Wtheta = (const float*)d_in[3];
    const float* Wg     = (const float*)d_in[4];
    const float* Wab    = (const float*)d_in[5];
    const float* Wmask  = (const float*)d_in[6];
    float* out = (float*)d_out;

    // workspace (~28.6 MB):
    //   ABt [4][4096][512] u16 = 16 MB  (dead after conv_gemm)
    //     ytp aliases ABt+0    (8 MB: [2 mh][4 b][256][2048] bf16, passB out)
    //     rs  aliases ABt+8MB  (128 KB f32, passA out)
    //   Wt 0.625 MB; phit/thetat/g 4 MB each
    u16*   ABt    = (u16*)d_ws;
    u16*   ytp    = ABt;
    float* rs     = (float*)(ABt + 4194304);
    u16*   Wt     = ABt + 8388608;
    u16*   phit   = Wt + 327680;
    u16*   thetat = phit + 2097152;
    u16*   g      = thetat + 2097152;

    prep_w<<<dim3(640), 256, 0, stream>>>(Wphi, Wtheta, Wg, Wab, Wt);

    prep_abt<<<dim3(64, 4), 256, 0, stream>>>(A, Bx, ABt);

    conv_gemm<<<dim3(64, 10, 4), 256, 0, stream>>>(
        Wt, ABt, phit, thetat, g, out);

    passA_mfma<<<dim3(32, 4, 4), 256, 0, stream>>>(phit, thetat, rs);

    g_scale<<<dim3(8, 32, 4), 256, 0, stream>>>(rs, g);

    passB_mfma<<<dim3(32, 2, 4), 256, 0, stream>>>(phit, thetat, g, ytp);

    mask_add_kernel<<<dim3(16, 32, 4), 256, 0, stream>>>(ytp, Wmask, out);
}

// Round 7
// 256.583 us; speedup vs baseline: 1.1092x; 1.1092x over previous
//
#include <hip/hip_runtime.h>
#include <hip/hip_bf16.h>

#define B_    4
#define C_    256
#define HW    4096
#define N_    2048   // seq len after the (b,256,2048) reinterpretation
#define BSTR  524288 // 256*2048 elements per batch for phit/thetat/g/Yt

typedef unsigned short u16;
using f32x4 = __attribute__((ext_vector_type(4))) float;
using u32x4 = __attribute__((ext_vector_type(4))) unsigned int;

__device__ __forceinline__ float bf2f(u16 u) {
    return __uint_as_float(((unsigned)u) << 16);
}
__device__ __forceinline__ u16 f2bf(float f) {
    unsigned x = __float_as_uint(f);
    x += 0x7fff + ((x >> 16) & 1);   // RNE
    return (u16)(x >> 16);
}

// MFMA via inline asm. Hazards handled manually: chained same-acc MFMAs need
// no waits; VALU reads of acc go through mfma_fence; VALU-written operands
// get an s_nop-prefixed variant.
__device__ __forceinline__ void mfma_bf16(f32x4& acc, u32x4 a, u32x4 b) {
    asm volatile("v_mfma_f32_16x16x32_bf16 %0, %1, %2, %0"
                 : "+v"(acc) : "v"(a), "v"(b));
}
__device__ __forceinline__ void mfma_bf16_vsrc(f32x4& acc, u32x4 a, u32x4 b) {
    asm volatile("s_nop 1\n\tv_mfma_f32_16x16x32_bf16 %0, %1, %2, %0"
                 : "+v"(acc) : "v"(a), "v"(b));
}
__device__ __forceinline__ void mfma_fence(f32x4& x) {
    asm volatile("s_nop 7\n\ts_nop 7" : "+v"(x));
}

// ---------------------------------------------------------------------------
// prep_w: pack weights into Wt [640][512] bf16, k-fastest.
// ---------------------------------------------------------------------------
__global__ __launch_bounds__(256) void prep_w(
    const float* __restrict__ Wphi, const float* __restrict__ Wtheta,
    const float* __restrict__ Wg, const float* __restrict__ Wab,
    u16* __restrict__ Wt)
{
    const int row = blockIdx.x;          // 0..639
    const int t   = threadIdx.x;
    #pragma unroll
    for (int i = 0; i < 2; ++i) {
        const int col = i * 256 + t;
        float v;
        if (row < 128)      v = (col < 256)  ? Wphi[row * 256 + col] : 0.f;
        else if (row < 256) v = (col >= 256) ? Wtheta[(row - 128) * 256 + (col - 256)] : 0.f;
        else if (row < 384) v = Wg[(row - 256) * 512 + col];
        else                v = Wab[(row - 384) * 512 + col];
        Wt[row * 512 + col] = f2bf(v);
    }
}

// ---------------------------------------------------------------------------
// prep_abt: cast+transpose A,B (f32 [b][256][4096]) -> ABt bf16 [b][4096][512]
// ---------------------------------------------------------------------------
__global__ __launch_bounds__(256) void prep_abt(
    const float* __restrict__ A, const float* __restrict__ Bx,
    u16* __restrict__ ABt)
{
    __shared__ u16 L[64][528];
    const int t = threadIdx.x, pb = blockIdx.x, b = blockIdx.y;
    const int p0 = pb * 64;
    const int pl = t & 63, cg = t >> 6;
    const float* Ab = A  + (size_t)b * C_ * HW;
    const float* Bb = Bx + (size_t)b * C_ * HW;

    for (int i = 0; i < 64; ++i) {
        const int c = cg + i * 4;
        L[pl][c]       = f2bf(Ab[c * HW + p0 + pl]);
        L[pl][256 + c] = f2bf(Bb[c * HW + p0 + pl]);
    }
    __syncthreads();
    u16* dst = ABt + ((size_t)b * 4096 + p0) * 512;
    #pragma unroll
    for (int i = 0; i < 16; ++i) {
        const int idx = i * 256 + t;
        const int row = idx >> 6, ch = idx & 63;
        *(uint4*)&dst[row * 512 + ch * 8] = *(const uint4*)&L[row][ch * 8];
    }
}

// ---------------------------------------------------------------------------
// conv_gemm: C[o][p] = sum_k Wt[o][k] * ABt[p][k]  (per batch), o in [0,640).
// ---------------------------------------------------------------------------
__global__ __launch_bounds__(256) void conv_gemm(
    const u16* __restrict__ Wt, const u16* __restrict__ ABt,
    u16* __restrict__ phit, u16* __restrict__ thetat,
    u16* __restrict__ g, float* __restrict__ out)
{
    __shared__ __align__(16) u16 shW[64 * 128];
    __shared__ __align__(16) u16 shAB[64 * 128];
    const int t = threadIdx.x, pb = blockIdx.x, nb = blockIdx.y, b = blockIdx.z;
    const int lane = t & 63, w = t >> 6, lo = lane & 15, hi = lane >> 4;
    const u16* Wb = Wt + nb * 64 * 512;
    const u16* Ab = ABt + ((size_t)b * 4096 + pb * 64) * 512;

    f32x4 acc[4];
    #pragma unroll
    for (int ot = 0; ot < 4; ++ot) acc[ot] = (f32x4){0.f, 0.f, 0.f, 0.f};

    for (int ks = 0; ks < 4; ++ks) {
        __syncthreads();
        #pragma unroll
        for (int i = 0; i < 4; ++i) {
            const int q = i * 256 + t;
            const int row = q >> 4, c16 = (q & 15) * 8;
            const int sw = (row & 7) << 3;
            *(uint4*)&shW[row * 128 + (c16 ^ sw)]  = *(const uint4*)&Wb[row * 512 + ks * 128 + c16];
            *(uint4*)&shAB[row * 128 + (c16 ^ sw)] = *(const uint4*)&Ab[row * 512 + ks * 128 + c16];
        }
        __syncthreads();
        u32x4 bfr[4];
        {
            const int row = w * 16 + lo, sw = (row & 7) << 3;
            #pragma unroll
            for (int kf = 0; kf < 4; ++kf)
                bfr[kf] = *(const u32x4*)&shAB[row * 128 + ((kf * 32 + hi * 8) ^ sw)];
        }
        #pragma unroll
        for (int ot = 0; ot < 4; ++ot) {
            const int row = ot * 16 + lo, sw = (row & 7) << 3;
            #pragma unroll
            for (int kf = 0; kf < 4; ++kf) {
                const u32x4 a = *(const u32x4*)&shW[row * 128 + ((kf * 32 + hi * 8) ^ sw)];
                mfma_bf16(acc[ot], a, bfr[kf]);
            }
        }
    }

    const int p_global = pb * 64 + w * 16 + lo;
    const int m = p_global & 2047, h = p_global >> 11;
    #pragma unroll
    for (int ot = 0; ot < 4; ++ot) {
        mfma_fence(acc[ot]);
        const int ob = nb * 64 + ot * 16 + hi * 4;
        if (nb < 2) {
            ushort4 v;
            v.x = f2bf(acc[ot][0]); v.y = f2bf(acc[ot][1]);
            v.z = f2bf(acc[ot][2]); v.w = f2bf(acc[ot][3]);
            *(ushort4*)&phit[(size_t)b * BSTR + m * 256 + h * 128 + ob] = v;
        } else if (nb < 4) {
            ushort4 v;
            v.x = f2bf(acc[ot][0]); v.y = f2bf(acc[ot][1]);
            v.z = f2bf(acc[ot][2]); v.w = f2bf(acc[ot][3]);
            *(ushort4*)&thetat[(size_t)b * BSTR + m * 256 + h * 128 + (ob - 128)] = v;
        } else if (nb < 6) {
            #pragma unroll
            for (int q = 0; q < 4; ++q)
                g[(size_t)b * BSTR + (ob - 256 + q) * HW + p_global] = f2bf(acc[ot][q]);
        } else {
            #pragma unroll
            for (int q = 0; q < 4; ++q)
                out[(size_t)b * C_ * HW + (size_t)(ob - 384 + q) * HW + p_global] = acc[ot][q];
        }
    }
}

// ---------------------------------------------------------------------------
// Pass A (MFMA): partial row-sums of exp(S), S[m][n] = sum_c phit[m][c]*thetat[n][c].
// ---------------------------------------------------------------------------
__global__ __launch_bounds__(256) void passA_mfma(
    const u16* __restrict__ phit, const u16* __restrict__ thetat,
    float* __restrict__ rs)
{
    __shared__ __align__(16) u16 shP[64 * 256];
    __shared__ __align__(16) u16 shT[64 * 256];
    const int t = threadIdx.x, b = blockIdx.z, nq = blockIdx.y, mb = blockIdx.x;
    const u16* Pb = phit   + b * BSTR + mb * 64 * 256;
    const u16* Tb = thetat + b * BSTR + nq * 512 * 256;

    #pragma unroll
    for (int i = 0; i < 8; ++i) {
        const int q = i * 256 + t;
        const int row = q >> 5, c16 = (q & 31) * 8;
        const uint4 v = *(const uint4*)&Pb[row * 256 + c16];
        *(uint4*)&shP[row * 256 + (c16 ^ ((row & 7) << 3))] = v;
    }
    __syncthreads();

    const int lane = t & 63, w = t >> 6, lo = lane & 15, hi = lane >> 4;
    u32x4 afr[8];
    {
        const int row = w * 16 + lo;
        #pragma unroll
        for (int kb = 0; kb < 8; ++kb)
            afr[kb] = *(const u32x4*)&shP[row * 256 + ((kb * 32 + hi * 8) ^ ((row & 7) << 3))];
    }

    float rsacc[4] = {0.f, 0.f, 0.f, 0.f};
    for (int nt = 0; nt < 8; ++nt) {
        __syncthreads();
        #pragma unroll
        for (int i = 0; i < 8; ++i) {
            const int q = i * 256 + t;
            const int row = q >> 5, c16 = (q & 31) * 8;
            const uint4 v = *(const uint4*)&Tb[(nt * 64 + row) * 256 + c16];
            *(uint4*)&shT[row * 256 + (c16 ^ ((row & 7) << 3))] = v;
        }
        __syncthreads();
        #pragma unroll
        for (int ns = 0; ns < 4; ++ns) {
            f32x4 acc = {0.f, 0.f, 0.f, 0.f};
            const int row = ns * 16 + lo;
            #pragma unroll
            for (int kb = 0; kb < 8; ++kb) {
                const u32x4 bfr = *(const u32x4*)&shT[row * 256 + ((kb * 32 + hi * 8) ^ ((row & 7) << 3))];
                mfma_bf16(acc, afr[kb], bfr);
            }
            mfma_fence(acc);
            rsacc[0] += __expf(acc.x); rsacc[1] += __expf(acc.y);
            rsacc[2] += __expf(acc.z); rsacc[3] += __expf(acc.w);
        }
    }
    #pragma unroll
    for (int q = 0; q < 4; ++q) {
        float v = rsacc[q];
        v += __shfl_xor(v, 1); v += __shfl_xor(v, 2);
        v += __shfl_xor(v, 4); v += __shfl_xor(v, 8);
        rsacc[q] = v;
    }
    if (lo == 0) {
        const int m = mb * 64 + w * 16 + hi * 4;
        float* dst = rs + (nq * 4 + b) * N_ + m;
        dst[0] = rsacc[0]; dst[1] = rsacc[1]; dst[2] = rsacc[2]; dst[3] = rsacc[3];
    }
}

// ---------------------------------------------------------------------------
// g_scale: g[c][m] *= inv[m]  (fold softmax denominator into the PV A-operand)
// ---------------------------------------------------------------------------
__global__ __launch_bounds__(256) void g_scale(
    const float* __restrict__ rs, u16* __restrict__ g)
{
    const int t  = threadIdx.x;
    const int mt = blockIdx.x;       // 8 m-tiles of 256
    const int cg = blockIdx.y;       // 32 groups of 8 c''-rows
    const int b  = blockIdx.z;
    const int m  = mt * 256 + t;
    const float* rp = rs + b * N_ + m;
    const float inv = 1.0f / (rp[0] + rp[8192] + rp[16384] + rp[24576]);
    u16* gb = g + (size_t)b * BSTR + cg * 8 * N_ + m;
    #pragma unroll
    for (int j = 0; j < 8; ++j)
        gb[j * N_] = f2bf(bf2f(gb[j * N_]) * inv);
}

// ---------------------------------------------------------------------------
// Pass B (MFMA, flash-style): S computed ONCE per (n,m); P=exp(S) in regs;
// PV over all 256 c''. grid (32 nb, 4 mq, 4 b) = 512 blocks (2/CU).
// Double-buffered LDS -> single barrier per m-step. Yt partial per m-quarter.
// ---------------------------------------------------------------------------
__global__ __launch_bounds__(256) void passB_mfma(
    const u16* __restrict__ phit, const u16* __restrict__ thetat,
    const u16* __restrict__ g, u16* __restrict__ ytp)
{
    // each buf: shPm [32][256] XOR-swz (8192 u16) + shG [256][36] pad (9216 u16)
    __shared__ __align__(16) u16 shBuf[2][17408];   // 68 KB
    const int t = threadIdx.x, b = blockIdx.z, mq = blockIdx.y, nb = blockIdx.x;
    const u16* Tb = thetat + b * BSTR + nb * 64 * 256;
    const u16* Pb = phit   + b * BSTR + mq * 512 * 256;
    const u16* Gb = g      + b * BSTR + mq * 512;
    const int lane = t & 63, w = t >> 6, lo = lane & 15, hi = lane >> 4;

    // prologue: stage theta (32 KB, spans buf0), extract B-frags, then free
    u16* shT = &shBuf[0][0];
    #pragma unroll
    for (int i = 0; i < 8; ++i) {
        const int q = i * 256 + t;
        const int row = q >> 5, c16 = (q & 31) * 8;
        const uint4 v = *(const uint4*)&Tb[row * 256 + c16];
        *(uint4*)&shT[row * 256 + (c16 ^ ((row & 7) << 3))] = v;
    }
    __syncthreads();
    u32x4 bfr[8];
    {
        const int row = w * 16 + lo;
        #pragma unroll
        for (int kb = 0; kb < 8; ++kb)
            bfr[kb] = *(const u32x4*)&shT[row * 256 + ((kb * 32 + hi * 8) ^ ((row & 7) << 3))];
    }
    __syncthreads();   // frags extracted -> buffers reusable

    f32x4 accY[16];
    #pragma unroll
    for (int ct = 0; ct < 16; ++ct) accY[ct] = (f32x4){0.f, 0.f, 0.f, 0.f};

    // prefetch m-step 0
    uint4 vp[4], vg[4];
    #pragma unroll
    for (int i = 0; i < 4; ++i) {
        const int q = i * 256 + t;
        vp[i] = *(const uint4*)&Pb[(q >> 5) * 256 + (q & 31) * 8];
    }
    #pragma unroll
    for (int qd = 0; qd < 4; ++qd)
        vg[qd] = *(const uint4*)&Gb[(size_t)t * N_ + qd * 8];

    for (int mt = 0; mt < 16; ++mt) {
        u16* shPm = &shBuf[mt & 1][0];
        u16* shG  = &shBuf[mt & 1][8192];

        // stage this step from prefetched regs
        #pragma unroll
        for (int i = 0; i < 4; ++i) {
            const int q = i * 256 + t;
            const int row = q >> 5, c16 = (q & 31) * 8;
            *(uint4*)&shPm[row * 256 + (c16 ^ ((row & 7) << 3))] = vp[i];
        }
        {
            u16* gr = &shG[t * 36];
            *(uint2*)&gr[0]  = make_uint2(vg[0].x, vg[0].y);
            *(uint2*)&gr[4]  = make_uint2(vg[0].z, vg[0].w);
            *(uint2*)&gr[8]  = make_uint2(vg[1].x, vg[1].y);
            *(uint2*)&gr[12] = make_uint2(vg[1].z, vg[1].w);
            *(uint2*)&gr[16] = make_uint2(vg[2].x, vg[2].y);
            *(uint2*)&gr[20] = make_uint2(vg[2].z, vg[2].w);
            *(uint2*)&gr[24] = make_uint2(vg[3].x, vg[3].y);
            *(uint2*)&gr[28] = make_uint2(vg[3].z, vg[3].w);
        }
        // prefetch next m-step (completes during compute)
        const int mtn = (mt < 15) ? mt + 1 : 15;
        #pragma unroll
        for (int i = 0; i < 4; ++i) {
            const int q = i * 256 + t;
            vp[i] = *(const uint4*)&Pb[(mtn * 32 + (q >> 5)) * 256 + (q & 31) * 8];
        }
        #pragma unroll
        for (int qd = 0; qd < 4; ++qd)
            vg[qd] = *(const uint4*)&Gb[(size_t)t * N_ + mtn * 32 + qd * 8];

        __syncthreads();   // single barrier per step (dbuf makes it safe)

        // S: this wave's 16 n-cols vs 32 m-rows
        __builtin_amdgcn_s_setprio(1);
        f32x4 s0 = {0.f, 0.f, 0.f, 0.f}, s1 = {0.f, 0.f, 0.f, 0.f};
        {
            const int row = lo;
            #pragma unroll
            for (int kb = 0; kb < 8; ++kb) {
                const u32x4 a = *(const u32x4*)&shPm[row * 256 + ((kb * 32 + hi * 8) ^ ((row & 7) << 3))];
                mfma_bf16(s0, a, bfr[kb]);
            }
        }
        {
            const int row = 16 + lo;
            #pragma unroll
            for (int kb = 0; kb < 8; ++kb) {
                const u32x4 a = *(const u32x4*)&shPm[row * 256 + ((kb * 32 + hi * 8) ^ ((row & 7) << 3))];
                mfma_bf16(s1, a, bfr[kb]);
            }
        }
        __builtin_amdgcn_s_setprio(0);
        mfma_fence(s0); mfma_fence(s1);

        // P = exp(S) (denominator pre-folded into g); pack bf16
        float p0[4], p1[4];
        #pragma unroll
        for (int q = 0; q < 4; ++q) {
            p0[q] = __expf(s0[q]);
            p1[q] = __expf(s1[q]);
        }
        u32x4 pf;
        pf[0] = (unsigned)f2bf(p0[0]) | ((unsigned)f2bf(p0[1]) << 16);
        pf[1] = (unsigned)f2bf(p0[2]) | ((unsigned)f2bf(p0[3]) << 16);
        pf[2] = (unsigned)f2bf(p1[0]) | ((unsigned)f2bf(p1[1]) << 16);
        pf[3] = (unsigned)f2bf(p1[2]) | ((unsigned)f2bf(p1[3]) << 16);

        // PV over all 16 c''-tiles (G A-frag uses same kmap as pf packing)
        __builtin_amdgcn_s_setprio(1);
        #pragma unroll
        for (int ct = 0; ct < 16; ++ct) {
            const int row = ct * 16 + lo;
            const uint2 a0 = *(const uint2*)&shG[row * 36 + hi * 4];
            const uint2 a1 = *(const uint2*)&shG[row * 36 + 16 + hi * 4];
            u32x4 gf; gf[0] = a0.x; gf[1] = a0.y; gf[2] = a1.x; gf[3] = a1.y;
            if (ct == 0) mfma_bf16_vsrc(accY[ct], gf, pf);  // pf VALU-written
            else         mfma_bf16(accY[ct], gf, pf);
        }
        __builtin_amdgcn_s_setprio(0);
    }

    // epilogue: Yt partial [mq][b][c''][n]
    u16* Yb = ytp + ((size_t)mq * B_ + b) * BSTR;
    const int col = nb * 64 + w * 16 + lo;
    #pragma unroll
    for (int ct = 0; ct < 16; ++ct) {
        mfma_fence(accY[ct]);
        const int crow = ct * 16 + hi * 4;
        #pragma unroll
        for (int q = 0; q < 4; ++q)
            Yb[(crow + q) * N_ + col] = f2bf(accY[ct][q]);
    }
}

// ---------------------------------------------------------------------------
// mask_add: out[o][p] += sum_k W_mask[o][k] * (Y0+Y1+Y2+Y3)(128x4096)[k][p]
// ---------------------------------------------------------------------------
__global__ __launch_bounds__(256) void mask_add_kernel(
    const u16* __restrict__ ytp, const float* __restrict__ Wm,
    float* __restrict__ out)
{
    const int p  = blockIdx.x * 256 + threadIdx.x;
    const int og = blockIdx.y;
    const int b  = blockIdx.z;
    const u16* Y0 = ytp + (size_t)(0 * B_ + b) * BSTR;
    const u16* Y1 = ytp + (size_t)(1 * B_ + b) * BSTR;
    const u16* Y2 = ytp + (size_t)(2 * B_ + b) * BSTR;
    const u16* Y3 = ytp + (size_t)(3 * B_ + b) * BSTR;

    float acc[8] = {};
    for (int k = 0; k < 128; ++k) {
        const float y = bf2f(Y0[k * HW + p]) + bf2f(Y1[k * HW + p])
                      + bf2f(Y2[k * HW + p]) + bf2f(Y3[k * HW + p]);
        #pragma unroll
        for (int j = 0; j < 8; ++j)
            acc[j] = fmaf(Wm[(og * 8 + j) * 128 + k], y, acc[j]);
    }
    float* ob = out + (size_t)b * C_ * HW;
    #pragma unroll
    for (int j = 0; j < 8; ++j)
        ob[(og * 8 + j) * HW + p] += acc[j];
}

// ---------------------------------------------------------------------------
extern "C" void kernel_launch(void* const* d_in, const int* in_sizes, int n_in,
                              void* d_out, int out_size, void* d_ws, size_t ws_size,
                              hipStream_t stream)
{
    const float* A      = (const float*)d_in[0];
    const float* Bx     = (const float*)d_in[1];
    const float* Wphi   = (const float*)d_in[2];
    const float* Wtheta = (const float*)d_in[3];
    const float* Wg     = (const float*)d_in[4];
    const float* Wab    = (const float*)d_in[5];
    const float* Wmask  = (const float*)d_in[6];
    float* out = (float*)d_out;

    // workspace (~28.75 MB):
    //   ABt [4][4096][512] u16 = 16 MB (dead after conv_gemm)
    //     ytp aliases ABt: [4 mq][4 b][256][2048] bf16 = 16 MB (passB out)
    //   Wt 0.625 MB; phit/thetat/g 4 MB each; rs 128 KB at the end
    u16*   ABt    = (u16*)d_ws;
    u16*   ytp    = ABt;
    u16*   Wt     = ABt + 8388608;
    u16*   phit   = Wt + 327680;
    u16*   thetat = phit + 2097152;
    u16*   g      = thetat + 2097152;
    float* rs     = (float*)(g + 2097152);

    prep_w<<<dim3(640), 256, 0, stream>>>(Wphi, Wtheta, Wg, Wab, Wt);

    prep_abt<<<dim3(64, 4), 256, 0, stream>>>(A, Bx, ABt);

    conv_gemm<<<dim3(64, 10, 4), 256, 0, stream>>>(
        Wt, ABt, phit, thetat, g, out);

    passA_mfma<<<dim3(32, 4, 4), 256, 0, stream>>>(phit, thetat, rs);

    g_scale<<<dim3(8, 32, 4), 256, 0, stream>>>(rs, g);

    passB_mfma<<<dim3(32, 4, 4), 256, 0, stream>>>(phit, thetat, g, ytp);

    mask_add_kernel<<<dim3(16, 32, 4), 256, 0, stream>>>(ytp, Wmask, out);
}